// Round 6
// baseline (142.515 us; speedup 1.0000x reference)
//
#include <hip/hip_runtime.h>
#include <hip/hip_bf16.h>

// Grouped masked GEMM (DeepSeekMOE up/gate + down), fp32 in/out, bf16 MFMA.
// G=8, M=32. up/gate: K=4096,N=2816. down: K=1408,N=4096. out: [G,32,5632] f32.
//
// R5: 1 KB DRAM row-visits for up-proj W. Each K-tile (BK=256) is staged as
// two 16-row sub-stages sharing one 16 KB LDS buffer (n-frag 0 uses W rows
// 0-15, n-frag 1 uses rows 16-31 — independent in the MFMA). One DMA instr
// = one row's 1 KB contiguous. X loaded once per tile, pre-converted to bf16,
// reused by both sub-stages. Down-proj: BK=128 (512 B visits), same template.
// All 1728 one-wave units co-resident (16 KB/block -> 108 KB/CU), barrier-free,
// XCD-affine (g = b&7), 11:16 up/down interleave for per-CU work balance.

#define G_    8
#define M_    32
#define KUG   4096
#define NUG   2816
#define KDN   1408
#define NDN   4096
#define NOUT  (NUG + NDN)      // 5632
#define UPT   (NUG / 32)       // 88 up units per group
#define DNT   (NDN / 32)       // 128 down units per group
#define UPG   (UPT + DNT)      // 216 = 8 periods of 27 (11 up + 16 down)

typedef __attribute__((ext_vector_type(8))) short bf16x8;
typedef __attribute__((ext_vector_type(4))) float f32x4;

typedef __attribute__((address_space(3))) float        lds_f32;
typedef const __attribute__((address_space(1))) float  gbl_f32;

// fp32 -> bf16 RNE via compiler (m240: don't hand-write cvt_pk asm).
__device__ __forceinline__ short f2bf(float x) {
  union { __hip_bfloat16 h; short s; } u;
  u.h = __hip_bfloat16(x);
  return u.s;
}

__device__ __forceinline__ bf16x8 cvt8(f32x4 lo, f32x4 hi) {
  bf16x8 o;
#pragma unroll
  for (int j = 0; j < 4; ++j) { o[j] = f2bf(lo[j]); o[4 + j] = f2bf(hi[j]); }
  return o;
}

// Stage 16 W rows x BK floats into LDS. Row-visit = BK*4 contiguous bytes
// (BK=256 -> 1 KB, one instr per row; BK=128 -> 512 B, two rows per instr).
// LDS dest linear (gload_lds rule); bank-swizzle via source-granule XOR
// (physical granule p of row holds global granule p ^ (row&7); involution).
template<int BK>
__device__ __forceinline__ void stage16(const float* wrows, float* wbuf,
                                        int K, int k0, int t) {
  constexpr int GPR = BK / 4;             // 16B granules per row
  constexpr int NI  = 16 * GPR / 64;      // wave instrs
#pragma unroll
  for (int i = 0; i < NI; ++i) {
    int gid = i * 64 + t;
    int row = gid / GPR;
    int q   = gid % GPR;
    int qs  = q ^ (row & 7);
    __builtin_amdgcn_global_load_lds(
        (gbl_f32*)(wrows + (size_t)row * K + k0 + qs * 4),
        (lds_f32*)(wbuf + gid * 4), 16, 0, 0);
  }
}

// Consume one 16-row sub-stage: NKS k-steps, 2 MFMA each (m-frag 0 and 1).
template<int NKS>
__device__ __forceinline__ void comp16(const float* wbuf, const bf16x8 (&xb)[2][NKS],
                                       int r, int q4, int s,
                                       f32x4& accM0, f32x4& accM1) {
  constexpr int BK = NKS * 32;
#pragma unroll
  for (int ks = 0; ks < NKS; ++ks) {
    int g0 = (ks * 4 + q4) * 2;           // lane's logical 16B granule pair
    const float* rowp = wbuf + (size_t)r * BK;
    f32x4 wlo = *(const f32x4*)(rowp + (((g0)     ^ s) << 2));
    f32x4 whi = *(const f32x4*)(rowp + (((g0 + 1) ^ s) << 2));
    bf16x8 bb = cvt8(wlo, whi);
    accM0 = __builtin_amdgcn_mfma_f32_16x16x32_bf16(xb[0][ks], bb, accM0, 0, 0, 0);
    accM1 = __builtin_amdgcn_mfma_f32_16x16x32_bf16(xb[1][ks], bb, accM1, 0, 0, 0);
  }
}

template<int NKS, int NIT>
__device__ __forceinline__ void run_unit(const float* wg, const float* xg,
                                         float* wbuf, int K, int t,
                                         f32x4& acc00, f32x4& acc01,
                                         f32x4& acc10, f32x4& acc11) {
  constexpr int BK = NKS * 32;
  int r = t & 15, q4 = t >> 4, s = r & 7;
  for (int it = 0; it < NIT; ++it) {
    int k0 = it * BK;

    // Sub-stage A: W rows 0-15 (DMA), X tile (global->reg, L2/L3-served).
    stage16<BK>(wg, wbuf, K, k0, t);
    f32x4 xv[2][NKS][2];
#pragma unroll
    for (int mf = 0; mf < 2; ++mf)
#pragma unroll
      for (int ks = 0; ks < NKS; ++ks) {
        const float* xp = xg + (size_t)(mf * 16 + r) * K + k0 + ks * 32 + q4 * 8;
        xv[mf][ks][0] = *(const f32x4*)xp;
        xv[mf][ks][1] = *(const f32x4*)(xp + 4);
      }
    // gload_lds -> ds_read dep is invisible to the compiler (rule #18).
    asm volatile("s_waitcnt vmcnt(0)" ::: "memory");
    __builtin_amdgcn_sched_barrier(0);

    bf16x8 xb[2][NKS];                    // convert X once, reuse in both halves
#pragma unroll
    for (int mf = 0; mf < 2; ++mf)
#pragma unroll
      for (int ks = 0; ks < NKS; ++ks)
        xb[mf][ks] = cvt8(xv[mf][ks][0], xv[mf][ks][1]);

    comp16<NKS>(wbuf, xb, r, q4, s, acc00, acc10);   // n-frag 0 (cols r)

    // Sub-stage B: W rows 16-31 into the SAME buffer. Safe: comp A's ds_reads
    // issued before these DMAs (in-order wave); DMA LDS-write lags by >=900cy.
    stage16<BK>(wg + (size_t)16 * K, wbuf, K, k0, t);
    asm volatile("s_waitcnt vmcnt(0)" ::: "memory");
    __builtin_amdgcn_sched_barrier(0);

    comp16<NKS>(wbuf, xb, r, q4, s, acc01, acc11);   // n-frag 1 (cols 16+r)
  }
}

__global__ __launch_bounds__(64, 2) void moe_masked_gemm(
    const float* __restrict__ x_ug, const float* __restrict__ w_ug,
    const float* __restrict__ x_dn, const float* __restrict__ w_dn,
    const int* __restrict__ masked_m, float* __restrict__ out) {
  __shared__ float wbuf[16 * 256];   // 16 KB -> 6.75 blocks/CU all-resident

  int b = blockIdx.x;
  int g = b & 7;        // group -> XCD affinity (consecutive ids round-robin XCDs)
  int v = b >> 3;       // unit slot 0..215 within group
  // 11:16 interleave (704:1024 exactly): per-XCD dispatch stream mixes long
  // up-units (32 K-iters' worth) with short down-units for per-CU balance.
  int period = v / 27, slot = v - period * 27;
  int u = (slot < 11) ? (period * 11 + slot) : (UPT + period * 16 + (slot - 11));

  const float* wg;
  const float* xg;
  int K, n0, colOff;
  bool is_up = (u < UPT);
  if (is_up) {
    K = KUG; n0 = u * 32; colOff = 0;
    wg = w_ug + ((size_t)g * NUG + n0) * KUG;
    xg = x_ug + (size_t)g * M_ * KUG;
  } else {
    int ud = u - UPT;
    K = KDN; n0 = ud * 32; colOff = NUG;
    wg = w_dn + ((size_t)g * NDN + n0) * KDN;
    xg = x_dn + (size_t)g * M_ * KDN;
  }

  int mm = masked_m[g];
  int t  = threadIdx.x;
  int r  = t & 15, q4 = t >> 4;

  f32x4 acc00 = {0.f, 0.f, 0.f, 0.f}, acc01 = {0.f, 0.f, 0.f, 0.f};
  f32x4 acc10 = {0.f, 0.f, 0.f, 0.f}, acc11 = {0.f, 0.f, 0.f, 0.f};

  if (mm != 0) {                      // mm==0: skip ALL reads, write zeros below
    if (is_up) run_unit<8, KUG / 256>(wg, xg, wbuf, K, t, acc00, acc01, acc10, acc11);
    else       run_unit<4, KDN / 128>(wg, xg, wbuf, K, t, acc00, acc01, acc10, acc11);
  }

  // Epilogue. C/D layout: col = lane&15, row = (lane>>4)*4 + i (m89-verified).
  // Lane stores cols n0+r, n0+16+r for rows m = mf*16 + q4*4 + i; mask m >= mm.
  float* outg = out + (size_t)g * M_ * NOUT + colOff + n0;
#pragma unroll
  for (int i = 0; i < 4; ++i) {
    int m0 = q4 * 4 + i;         // rows 0..15  (accM0 = acc0*)
    int m1 = 16 + m0;            // rows 16..31 (acc1*)
    outg[(size_t)m0 * NOUT + r]      = (m0 < mm) ? acc00[i] : 0.f;
    outg[(size_t)m0 * NOUT + 16 + r] = (m0 < mm) ? acc01[i] : 0.f;
    outg[(size_t)m1 * NOUT + r]      = (m1 < mm) ? acc10[i] : 0.f;
    outg[(size_t)m1 * NOUT + 16 + r] = (m1 < mm) ? acc11[i] : 0.f;
  }
}

extern "C" void kernel_launch(void* const* d_in, const int* in_sizes, int n_in,
                              void* d_out, int out_size, void* d_ws, size_t ws_size,
                              hipStream_t stream) {
  const float* x_ug     = (const float*)d_in[0];
  const float* w_ug     = (const float*)d_in[1];
  const float* x_dn     = (const float*)d_in[2];
  const float* w_dn     = (const float*)d_in[3];
  const int*   masked_m = (const int*)d_in[4];
  float*       out      = (float*)d_out;

  moe_masked_gemm<<<dim3(G_ * UPG), dim3(64), 0, stream>>>(
      x_ug, w_ug, x_dn, w_dn, masked_m, out);
}

// Round 7
// 136.998 us; speedup vs baseline: 1.0403x; 1.0403x over previous
//
#include <hip/hip_runtime.h>
#include <hip/hip_bf16.h>

// Grouped masked GEMM (DeepSeekMOE up/gate + down), fp32 in/out, bf16 MFMA.
// G=8, M=32. up/gate: K=4096,N=2816. down: K=1408,N=4096. out: [G,32,5632] f32.
//
// R6: base = R4 (best, 122.9us): 1-wave blocks, W staged via global_load_lds
// BK=128 (512B row visits), single LDS buffer, per-iter vmcnt(0), barrier-free,
// XCD-affine. Changes (one axis - shrink X-side traffic 8x):
//   * n=64 units (864 blocks): X logical reads halve, MFMA/X-byte doubles.
//   * X pre-converted to bf16 into d_ws by a prologue kernel: X bytes halve
//     again, per-iter X cvt VALU deleted (frags load as 16B in MFMA layout).
//   * Bresenham 11:16 up/down interleave for per-CU work balance.

#define G_    8
#define M_    32
#define KUG   4096
#define NUG   2816
#define KDN   1408
#define NDN   4096
#define NOUT  (NUG + NDN)      // 5632
#define BN    64
#define BK    128
#define UPT   (NUG / BN)       // 44 up units per group
#define DNT   (NDN / BN)       // 64 down units per group
#define UPG   (UPT + DNT)      // 108 units per group; grid = 864
#define XUG_E (G_ * M_ * KUG)  // 1048576
#define XDN_E (G_ * M_ * KDN)  // 360448
#define XBF_BYTES ((size_t)(XUG_E + XDN_E) * 2)   // 2,818,048 B

typedef __attribute__((ext_vector_type(8))) short bf16x8;
typedef __attribute__((ext_vector_type(4))) float f32x4;

typedef __attribute__((address_space(3))) float        lds_f32;
typedef const __attribute__((address_space(1))) float  gbl_f32;

// fp32 -> bf16 RNE via compiler (m240: don't hand-write cvt_pk asm).
__device__ __forceinline__ short f2bf(float x) {
  union { __hip_bfloat16 h; short s; } u;
  u.h = __hip_bfloat16(x);
  return u.s;
}

__device__ __forceinline__ bf16x8 cvt8(f32x4 lo, f32x4 hi) {
  bf16x8 o;
#pragma unroll
  for (int j = 0; j < 4; ++j) { o[j] = f2bf(lo[j]); o[4 + j] = f2bf(hi[j]); }
  return o;
}

// Prologue: f32 -> bf16, 8 elems/thread (launched with exact grid).
__global__ void cvt_x_kernel(const float* __restrict__ src, short* __restrict__ dst,
                             int n8) {
  int i = blockIdx.x * 256 + threadIdx.x;
  if (i < n8) {
    f32x4 lo = *(const f32x4*)(src + (size_t)i * 8);
    f32x4 hi = *(const f32x4*)(src + (size_t)i * 8 + 4);
    *(bf16x8*)(dst + (size_t)i * 8) = cvt8(lo, hi);
  }
}

template<bool XBF>
__global__ __launch_bounds__(64, 2) void moe_masked_gemm(
    const float* __restrict__ x_ug, const float* __restrict__ w_ug,
    const float* __restrict__ x_dn, const float* __restrict__ w_dn,
    const short* __restrict__ xbf_ug, const short* __restrict__ xbf_dn,
    const int* __restrict__ masked_m, float* __restrict__ out) {
  __shared__ float wbuf[BN * BK];   // 64 rows x 128 f32 = 32 KB -> still all-resident

  int b = blockIdx.x;
  int g = b & 7;                    // group -> XCD affinity
  int v = b >> 3;                   // unit slot 0..107 within group
  // Bresenham 11:16 interleave over 27-slot periods (4 periods = 44 up + 64 dn):
  // slot s is "up" iff (s*11)%27 < 11; ups_before(s) = (s*11+16)/27.
  int p = v / 27, s = v - p * 27;
  int ub = (s * 11 + 16) / 27;
  bool is_up = ((s * 11) % 27) < 11;

  const float* wg;
  const float* xf;
  const short* xq;
  int K, n0, colOff, NIT;
  if (is_up) {
    int u = p * 11 + ub;
    K = KUG; NIT = KUG / BK; n0 = u * BN; colOff = 0;
    wg = w_ug + ((size_t)g * NUG + n0) * KUG;
    xf = x_ug + (size_t)g * M_ * KUG;
    xq = xbf_ug + (size_t)g * M_ * KUG;
  } else {
    int d = p * 16 + (s - ub);
    K = KDN; NIT = KDN / BK; n0 = d * BN; colOff = NUG;
    wg = w_dn + ((size_t)g * NDN + n0) * KDN;
    xf = x_dn + (size_t)g * M_ * KDN;
    xq = xbf_dn + (size_t)g * M_ * KDN;
  }

  int mm = masked_m[g];
  int t  = threadIdx.x;
  int r  = t & 15, q4 = t >> 4;     // frag coords
  int sk = r & 7;                   // read-side swizzle key (== row&7, rows = nf*16+r)

  f32x4 acc[2][4];                  // [m-frag][n-frag], all indices compile-time
#pragma unroll
  for (int mf = 0; mf < 2; ++mf)
#pragma unroll
    for (int nf = 0; nf < 4; ++nf) acc[mf][nf] = (f32x4){0.f, 0.f, 0.f, 0.f};

  if (mm != 0) {                    // mm==0: skip ALL reads, epilogue writes zeros
    for (int it = 0; it < NIT; ++it) {
      int k0 = it * BK;

      // --- Stage W tile [64 rows][128] via gload_lds: instr i covers rows
      // {2i,2i+1}, 512B contiguous per row (R4-proven sweet spot). LDS dest
      // linear; bank-swizzle via source-granule XOR (granule q of row holds
      // global granule q ^ (row&7); involution, applied again on read).
#pragma unroll
      for (int i = 0; i < 32; ++i) {
        int gid = i * 64 + t;
        int row = gid >> 5;         // 32 granules per row
        int q   = gid & 31;
        int qs  = q ^ (row & 7);
        __builtin_amdgcn_global_load_lds(
            (gbl_f32*)(wg + (size_t)row * K + k0 + qs * 4),
            (lds_f32*)(wbuf + gid * 4), 16, 0, 0);
      }

      // --- X fragments. bf16 path: one 16B load each, already in MFMA layout.
      bf16x8 xb[2][4];              // [m-frag][k-step]
      if constexpr (XBF) {
#pragma unroll
        for (int mf = 0; mf < 2; ++mf)
#pragma unroll
          for (int ks = 0; ks < 4; ++ks)
            xb[mf][ks] = *(const bf16x8*)(xq + (size_t)(mf * 16 + r) * K +
                                          k0 + ks * 32 + q4 * 8);
      } else {
#pragma unroll
        for (int mf = 0; mf < 2; ++mf)
#pragma unroll
          for (int ks = 0; ks < 4; ++ks) {
            const float* xp = xf + (size_t)(mf * 16 + r) * K + k0 + ks * 32 + q4 * 8;
            xb[mf][ks] = cvt8(*(const f32x4*)xp, *(const f32x4*)(xp + 4));
          }
      }

      // gload_lds -> ds_read dep is invisible to the compiler (rule #18).
      asm volatile("s_waitcnt vmcnt(0)" ::: "memory");
      __builtin_amdgcn_sched_barrier(0);

      // --- Compute: 4 k-steps x (2 m-frags x 4 n-frags) = 32 MFMA.
#pragma unroll
      for (int ks = 0; ks < 4; ++ks) {
        int g0 = (ks * 4 + q4) * 2;
        int o0 = ((g0 ^ sk) << 2), o1 = (((g0 + 1) ^ sk) << 2);
#pragma unroll
        for (int nf = 0; nf < 4; ++nf) {
          const float* rowp = wbuf + (size_t)(nf * 16 + r) * BK;
          bf16x8 bb = cvt8(*(const f32x4*)(rowp + o0), *(const f32x4*)(rowp + o1));
          acc[0][nf] = __builtin_amdgcn_mfma_f32_16x16x32_bf16(xb[0][ks], bb, acc[0][nf], 0, 0, 0);
          acc[1][nf] = __builtin_amdgcn_mfma_f32_16x16x32_bf16(xb[1][ks], bb, acc[1][nf], 0, 0, 0);
        }
      }
      // Next iter's gload_lds can't pass this iter's ds_reads (same LDS buffer,
      // in-order wave) — R4-validated single-buffer reuse.
    }
  }

  // Epilogue. C/D layout: col = lane&15, row = (lane>>4)*4 + i (m89-verified).
  // Lane stores cols n0 + nf*16 + r for rows m = mf*16 + q4*4 + i; mask m >= mm.
  float* outg = out + (size_t)g * M_ * NOUT + colOff + n0;
#pragma unroll
  for (int i = 0; i < 4; ++i) {
    int m0 = q4 * 4 + i, m1 = 16 + m0;
    bool v0 = m0 < mm, v1 = m1 < mm;
#pragma unroll
    for (int nf = 0; nf < 4; ++nf) {
      outg[(size_t)m0 * NOUT + nf * 16 + r] = v0 ? acc[0][nf][i] : 0.f;
      outg[(size_t)m1 * NOUT + nf * 16 + r] = v1 ? acc[1][nf][i] : 0.f;
    }
  }
}

extern "C" void kernel_launch(void* const* d_in, const int* in_sizes, int n_in,
                              void* d_out, int out_size, void* d_ws, size_t ws_size,
                              hipStream_t stream) {
  const float* x_ug     = (const float*)d_in[0];
  const float* w_ug     = (const float*)d_in[1];
  const float* x_dn     = (const float*)d_in[2];
  const float* w_dn     = (const float*)d_in[3];
  const int*   masked_m = (const int*)d_in[4];
  float*       out      = (float*)d_out;

  short* xbf_ug = (short*)d_ws;
  short* xbf_dn = xbf_ug + XUG_E;

  if (ws_size >= XBF_BYTES) {
    cvt_x_kernel<<<dim3(XUG_E / 8 / 256), dim3(256), 0, stream>>>(x_ug, xbf_ug, XUG_E / 8);
    cvt_x_kernel<<<dim3(XDN_E / 8 / 256), dim3(256), 0, stream>>>(x_dn, xbf_dn, XDN_E / 8);
    moe_masked_gemm<true><<<dim3(G_ * UPG), dim3(64), 0, stream>>>(
        x_ug, w_ug, x_dn, w_dn, xbf_ug, xbf_dn, masked_m, out);
  } else {
    moe_masked_gemm<false><<<dim3(G_ * UPG), dim3(64), 0, stream>>>(
        x_ug, w_ug, x_dn, w_dn, xbf_ug, xbf_dn, masked_m, out);
  }
}

// Round 8
// 131.997 us; speedup vs baseline: 1.0797x; 1.0379x over previous
//
#include <hip/hip_runtime.h>
#include <hip/hip_bf16.h>

// Grouped masked GEMM (DeepSeekMOE up/gate + down), fp32 in/out, bf16 MFMA.
// G=8, M=32. up/gate: K=4096,N=2816. down: K=1408,N=4096. out: [G,32,5632] f32.
//
// R7 = R4 geometry (best, 122.9us: 1-wave blocks, n=32 units, W via
// global_load_lds BK=128 = 512B row-visits, single 16KB LDS buffer, 1728
// all-resident blocks, XCD-affine) + per-wave counted-vmcnt pipeline:
// vmcnt(8) waits only the current tile's W DMAs; next tile's stage+X issue
// BEFORE compute -> wave never has 0 VMEM ops outstanding (kills the ~30%
// per-wave dead time that R4/R6 occupancy comparison exposed).
// X pre-converted to bf16 in d_ws (8 X vm-ops/iter, no X cvt in MFMA window).

#define G_    8
#define M_    32
#define KUG   4096
#define NUG   2816
#define KDN   1408
#define NDN   4096
#define NOUT  (NUG + NDN)      // 5632
#define BN    32
#define BK    128
#define UPT   (NUG / BN)       // 88 up units per group
#define DNT   (NDN / BN)       // 128 down units per group
#define UPG   (UPT + DNT)      // 216 units per group; grid = 1728
#define XUG_E (G_ * M_ * KUG)  // 1048576
#define XDN_E (G_ * M_ * KDN)  // 360448
#define XBF_BYTES ((size_t)(XUG_E + XDN_E) * 2)

typedef __attribute__((ext_vector_type(8))) short bf16x8;
typedef __attribute__((ext_vector_type(4))) float f32x4;

typedef __attribute__((address_space(3))) float        lds_f32;
typedef const __attribute__((address_space(1))) float  gbl_f32;

#define SCHED0() __builtin_amdgcn_sched_barrier(0)

// fp32 -> bf16 RNE via compiler (m240: don't hand-write cvt_pk asm).
__device__ __forceinline__ short f2bf(float x) {
  union { __hip_bfloat16 h; short s; } u;
  u.h = __hip_bfloat16(x);
  return u.s;
}

__device__ __forceinline__ bf16x8 cvt8(f32x4 lo, f32x4 hi) {
  bf16x8 o;
#pragma unroll
  for (int j = 0; j < 4; ++j) { o[j] = f2bf(lo[j]); o[4 + j] = f2bf(hi[j]); }
  return o;
}

// Prologue: f32 -> bf16, 8 elems/thread.
__global__ void cvt_x_kernel(const float* __restrict__ src, short* __restrict__ dst,
                             int n8) {
  int i = blockIdx.x * 256 + threadIdx.x;
  if (i < n8) {
    f32x4 lo = *(const f32x4*)(src + (size_t)i * 8);
    f32x4 hi = *(const f32x4*)(src + (size_t)i * 8 + 4);
    *(bf16x8*)(dst + (size_t)i * 8) = cvt8(lo, hi);
  }
}

// Stage W tile [32 rows][BK=128 f32] via 16 gload_lds; instr i covers rows
// {2i,2i+1}, 512B contiguous per row (R4-proven). LDS dest linear (gload_lds
// rule); bank-swizzle by source-granule XOR: LDS[row][q] = glob[row][q^(row&7)].
__device__ __forceinline__ void stageW(const float* wg, float* wbuf, int K,
                                       int k0, int t) {
#pragma unroll
  for (int i = 0; i < 16; ++i) {
    int gid = i * 64 + t;
    int row = gid >> 5;           // 32 granules (16B) per row
    int q   = gid & 31;
    int qs  = q ^ (row & 7);
    __builtin_amdgcn_global_load_lds(
        (gbl_f32*)(wg + (size_t)row * K + k0 + qs * 4),
        (lds_f32*)(wbuf + gid * 4), 16, 0, 0);
  }
}

// 8 bf16 X fragment loads (one 16B load each, already in MFMA A-layout).
__device__ __forceinline__ void loadX(const short* xq, int K, int k0, int r,
                                      int q4, bf16x8 (&xb)[2][4]) {
#pragma unroll
  for (int mf = 0; mf < 2; ++mf)
#pragma unroll
    for (int ks = 0; ks < 4; ++ks)
      xb[mf][ks] = *(const bf16x8*)(xq + (size_t)(mf * 16 + r) * K +
                                    k0 + ks * 32 + q4 * 8);
}

// 16 ds_read_b128 of the W tile into registers (swizzle-corrected).
__device__ __forceinline__ void readW(const float* wbuf, int r, int q4, int sk,
                                      f32x4 (&wr)[2][4][2]) {
#pragma unroll
  for (int nf = 0; nf < 2; ++nf) {
    const float* rowp = wbuf + (size_t)(nf * 16 + r) * BK;
#pragma unroll
    for (int ks = 0; ks < 4; ++ks) {
      int g0 = (ks * 4 + q4) * 2;
      wr[nf][ks][0] = *(const f32x4*)(rowp + (((g0)     ^ sk) << 2));
      wr[nf][ks][1] = *(const f32x4*)(rowp + (((g0 + 1) ^ sk) << 2));
    }
  }
}

// cvt W + 16 MFMA (2 mf x 2 nf x 4 ks).
__device__ __forceinline__ void mfma_iter(const f32x4 (&wr)[2][4][2],
                                          const bf16x8 (&xb)[2][4],
                                          f32x4 (&acc)[2][2]) {
#pragma unroll
  for (int ks = 0; ks < 4; ++ks) {
    bf16x8 b0 = cvt8(wr[0][ks][0], wr[0][ks][1]);
    bf16x8 b1 = cvt8(wr[1][ks][0], wr[1][ks][1]);
    acc[0][0] = __builtin_amdgcn_mfma_f32_16x16x32_bf16(xb[0][ks], b0, acc[0][0], 0, 0, 0);
    acc[1][0] = __builtin_amdgcn_mfma_f32_16x16x32_bf16(xb[1][ks], b0, acc[1][0], 0, 0, 0);
    acc[0][1] = __builtin_amdgcn_mfma_f32_16x16x32_bf16(xb[0][ks], b1, acc[0][1], 0, 0, 0);
    acc[1][1] = __builtin_amdgcn_mfma_f32_16x16x32_bf16(xb[1][ks], b1, acc[1][1], 0, 0, 0);
  }
}

// Counted-vmcnt pipelined unit. Issue order per iter is PINNED (sched_barrier):
// [16 W DMAs][8 X loads] so that vmcnt(8) == "tile's W landed, X rides".
// Single-buffer reuse is safe: ds_reads of iter it are issued before the
// stage(it+1) DMAs; DMA LDS-writes land >=500cy after issue (R5-validated).
template<int NIT>
__device__ __forceinline__ void run_unit(const float* wg, const short* xq, int K,
                                         float* wbuf, int t, f32x4 (&acc)[2][2]) {
  int r = t & 15, q4 = t >> 4, sk = r & 7;
  bf16x8 xA[2][4], xB[2][4];

  stageW(wg, wbuf, K, 0, t);  SCHED0();
  loadX(xq, K, 0, r, q4, xA); SCHED0();

  constexpr int NP = NIT / 2;
  for (int p = 0; p < NP; ++p) {
    int itA = 2 * p, itB = itA + 1;
    // ---- iter A ----
    asm volatile("s_waitcnt vmcnt(8)" ::: "memory");  SCHED0();
    f32x4 wr[2][4][2];
    readW(wbuf, r, q4, sk, wr);                       SCHED0();
    stageW(wg, wbuf, K, itB * BK, t);                 SCHED0();
    loadX(xq, K, itB * BK, r, q4, xB);                SCHED0();
    mfma_iter(wr, xA, acc);     // compiler inserts lgkmcnt + vmcnt(24) for xA
    // ---- iter B ----
    asm volatile("s_waitcnt vmcnt(8)" ::: "memory");  SCHED0();
    readW(wbuf, r, q4, sk, wr);                       SCHED0();
    if (itB + 1 < NIT) {
      stageW(wg, wbuf, K, (itB + 1) * BK, t);         SCHED0();
      loadX(xq, K, (itB + 1) * BK, r, q4, xA);        SCHED0();
    }
    mfma_iter(wr, xB, acc);
  }
  if constexpr (NIT & 1) {      // tail (down: NIT=11); xA holds tile NIT-1
    asm volatile("s_waitcnt vmcnt(8)" ::: "memory");  SCHED0();
    f32x4 wr[2][4][2];
    readW(wbuf, r, q4, sk, wr);                       SCHED0();
    mfma_iter(wr, xA, acc);
  }
}

__global__ __launch_bounds__(64, 2) void moe_masked_gemm(
    const float* __restrict__ w_ug, const float* __restrict__ w_dn,
    const short* __restrict__ xbf_ug, const short* __restrict__ xbf_dn,
    const int* __restrict__ masked_m, float* __restrict__ out) {
  __shared__ float wbuf[BN * BK];   // 16 KB -> all 1728 blocks co-resident

  int b = blockIdx.x;
  int g = b & 7;                    // group -> XCD affinity (R4 mapping)
  int u = b >> 3;                   // unit 0..215: [0,88) up, [88,216) down

  const float* wg;
  const short* xq;
  int K, n0, colOff;
  bool is_up = (u < UPT);
  if (is_up) {
    K = KUG; n0 = u * BN; colOff = 0;
    wg = w_ug + ((size_t)g * NUG + n0) * KUG;
    xq = xbf_ug + (size_t)g * M_ * KUG;
  } else {
    int d = u - UPT;
    K = KDN; n0 = d * BN; colOff = NUG;
    wg = w_dn + ((size_t)g * NDN + n0) * KDN;
    xq = xbf_dn + (size_t)g * M_ * KDN;
  }

  int mm = masked_m[g];
  int t  = threadIdx.x;
  int r  = t & 15, q4 = t >> 4;

  f32x4 acc[2][2];
#pragma unroll
  for (int mf = 0; mf < 2; ++mf)
#pragma unroll
    for (int nf = 0; nf < 2; ++nf) acc[mf][nf] = (f32x4){0.f, 0.f, 0.f, 0.f};

  if (mm != 0) {                    // mm==0: skip ALL reads, epilogue writes zeros
    if (is_up) run_unit<KUG / BK>(wg, xq, K, wbuf, t, acc);   // 32 iters
    else       run_unit<KDN / BK>(wg, xq, K, wbuf, t, acc);   // 11 iters
  }

  // Epilogue. C/D layout: col = lane&15, row = (lane>>4)*4 + i (m89-verified).
  float* outg = out + (size_t)g * M_ * NOUT + colOff + n0;
#pragma unroll
  for (int i = 0; i < 4; ++i) {
    int m0 = q4 * 4 + i, m1 = 16 + m0;
    bool v0 = m0 < mm, v1 = m1 < mm;
#pragma unroll
    for (int nf = 0; nf < 2; ++nf) {
      outg[(size_t)m0 * NOUT + nf * 16 + r] = v0 ? acc[0][nf][i] : 0.f;
      outg[(size_t)m1 * NOUT + nf * 16 + r] = v1 ? acc[1][nf][i] : 0.f;
    }
  }
}

// Fallback (tiny ws): R4-style per-iter drain with f32 X straight from HBM.
__global__ __launch_bounds__(64, 2) void moe_masked_gemm_f32(
    const float* __restrict__ x_ug, const float* __restrict__ w_ug,
    const float* __restrict__ x_dn, const float* __restrict__ w_dn,
    const int* __restrict__ masked_m, float* __restrict__ out) {
  __shared__ float wbuf[BN * BK];
  int b = blockIdx.x, g = b & 7, u = b >> 3;
  const float* wg; const float* xf;
  int K, n0, colOff, NIT;
  bool is_up = (u < UPT);
  if (is_up) { K = KUG; NIT = KUG / BK; n0 = u * BN; colOff = 0;
    wg = w_ug + ((size_t)g * NUG + n0) * KUG; xf = x_ug + (size_t)g * M_ * KUG;
  } else { int d = u - UPT; K = KDN; NIT = KDN / BK; n0 = d * BN; colOff = NUG;
    wg = w_dn + ((size_t)g * NDN + n0) * KDN; xf = x_dn + (size_t)g * M_ * KDN; }
  int mm = masked_m[g], t = threadIdx.x, r = t & 15, q4 = t >> 4, sk = r & 7;
  f32x4 acc[2][2];
#pragma unroll
  for (int mf = 0; mf < 2; ++mf)
#pragma unroll
    for (int nf = 0; nf < 2; ++nf) acc[mf][nf] = (f32x4){0.f, 0.f, 0.f, 0.f};
  if (mm != 0) {
    for (int it = 0; it < NIT; ++it) {
      int k0 = it * BK;
      stageW(wg, wbuf, K, k0, t);
      bf16x8 xb[2][4];
#pragma unroll
      for (int mf = 0; mf < 2; ++mf)
#pragma unroll
        for (int ks = 0; ks < 4; ++ks) {
          const float* xp = xf + (size_t)(mf * 16 + r) * K + k0 + ks * 32 + q4 * 8;
          xb[mf][ks] = cvt8(*(const f32x4*)xp, *(const f32x4*)(xp + 4));
        }
      asm volatile("s_waitcnt vmcnt(0)" ::: "memory");
      SCHED0();
      f32x4 wr[2][4][2];
      readW(wbuf, r, q4, sk, wr);
      mfma_iter(wr, xb, acc);
    }
  }
  float* outg = out + (size_t)g * M_ * NOUT + colOff + n0;
#pragma unroll
  for (int i = 0; i < 4; ++i) {
    int m0 = q4 * 4 + i, m1 = 16 + m0;
    bool v0 = m0 < mm, v1 = m1 < mm;
#pragma unroll
    for (int nf = 0; nf < 2; ++nf) {
      outg[(size_t)m0 * NOUT + nf * 16 + r] = v0 ? acc[0][nf][i] : 0.f;
      outg[(size_t)m1 * NOUT + nf * 16 + r] = v1 ? acc[1][nf][i] : 0.f;
    }
  }
}

extern "C" void kernel_launch(void* const* d_in, const int* in_sizes, int n_in,
                              void* d_out, int out_size, void* d_ws, size_t ws_size,
                              hipStream_t stream) {
  const float* x_ug     = (const float*)d_in[0];
  const float* w_ug     = (const float*)d_in[1];
  const float* x_dn     = (const float*)d_in[2];
  const float* w_dn     = (const float*)d_in[3];
  const int*   masked_m = (const int*)d_in[4];
  float*       out      = (float*)d_out;

  short* xbf_ug = (short*)d_ws;
  short* xbf_dn = xbf_ug + XUG_E;

  if (ws_size >= XBF_BYTES) {
    cvt_x_kernel<<<dim3(XUG_E / 8 / 256), dim3(256), 0, stream>>>(x_ug, xbf_ug, XUG_E / 8);
    cvt_x_kernel<<<dim3(XDN_E / 8 / 256), dim3(256), 0, stream>>>(x_dn, xbf_dn, XDN_E / 8);
    moe_masked_gemm<<<dim3(G_ * UPG), dim3(64), 0, stream>>>(
        w_ug, w_dn, xbf_ug, xbf_dn, masked_m, out);
  } else {
    moe_masked_gemm_f32<<<dim3(G_ * UPG), dim3(64), 0, stream>>>(
        x_ug, w_ug, x_dn, w_dn, masked_m, out);
  }
}